// Round 1
// baseline (1501.774 us; speedup 1.0000x reference)
//
#include <hip/hip_runtime.h>
#include <math.h>

#define NN 100000
#define EE 800000
#define DH 128
#define NL 16
#define GEMM_GRID 1563
#define NSLOT 32

typedef __bf16 bf16x8 __attribute__((ext_vector_type(8)));
typedef __bf16 bf16x2 __attribute__((ext_vector_type(2)));
typedef float f32x4 __attribute__((ext_vector_type(4)));

// ---------------- CSR build ----------------
__global__ void k_hist(const int* __restrict__ row, int* __restrict__ cnt) {
    int e = blockIdx.x * 256 + threadIdx.x;
    if (e < EE) atomicAdd(&cnt[row[e]], 1);
}

__global__ void k_scan1(const int* __restrict__ cnt, int* __restrict__ rp, int* __restrict__ part) {
    __shared__ int buf[512];
    int tid = threadIdx.x;
    int i = blockIdx.x * 512 + tid;
    int v = (i < NN) ? cnt[i] : 0;
    buf[tid] = v;
    __syncthreads();
    for (int off = 1; off < 512; off <<= 1) {
        int x = (tid >= off) ? buf[tid - off] : 0;
        __syncthreads();
        buf[tid] += x;
        __syncthreads();
    }
    if (i < NN) rp[i] = buf[tid] - v;
    if (tid == 511) part[blockIdx.x] = buf[511];
}

__global__ void k_scan2(int* __restrict__ part, int nparts) {
    __shared__ int buf[256];
    int tid = threadIdx.x;
    int v = (tid < nparts) ? part[tid] : 0;
    buf[tid] = v;
    __syncthreads();
    for (int off = 1; off < 256; off <<= 1) {
        int x = (tid >= off) ? buf[tid - off] : 0;
        __syncthreads();
        buf[tid] += x;
        __syncthreads();
    }
    if (tid < nparts) part[tid] = buf[tid] - v;
}

__global__ void k_scan3(int* __restrict__ rp, const int* __restrict__ part) {
    int i = blockIdx.x * 512 + threadIdx.x;
    if (i < NN) rp[i] += part[blockIdx.x];
    if (i == 0) rp[NN] = EE;
}

// w prescaled by (1-ALPHA)=0.9 so the gather loop is a pure fma chain
__global__ void k_fill(const int* __restrict__ row, const int* __restrict__ col,
                       const float* __restrict__ w, const int* __restrict__ rp,
                       int* __restrict__ fil, int2* __restrict__ ep) {
    int e = blockIdx.x * 256 + threadIdx.x;
    if (e >= EE) return;
    int r = row[e];
    int pos = rp[r] + atomicAdd(&fil[r], 1);
    ep[pos] = make_int2(col[e], __float_as_int(0.9f * w[e]));
}

// ---------------- weight prep: split hi/lo bf16 + swizzle to MFMA fragment order ----------------
// frag[t][ks][lane][e] = M[k][j], j = t*16 + (lane&15), k = ks*32 + (lane>>4)*8 + e
__global__ void k_prep_w(const float* __restrict__ convW, const float* __restrict__ Win,
                         __bf16* __restrict__ Bhi, __bf16* __restrict__ Blo) {
    int l = blockIdx.x;
    const float* W;
    float beta, ob;
    if (l < NL) {
        beta = logf(0.5f / (float)(l + 1) + 1.0f);
        ob = 1.0f - beta;
        W = convW + (size_t)l * DH * DH;
    } else {
        beta = 1.0f;
        ob = 0.0f;
        W = Win;
    }
    __bf16* bh = Bhi + (size_t)l * DH * DH;
    __bf16* bl = Blo + (size_t)l * DH * DH;
    for (int i = threadIdx.x; i < DH * DH; i += 256) {
        int k = i >> 7, j = i & 127;
        float v = beta * W[i] + ((k == j) ? ob : 0.f);
        __bf16 hv = (__bf16)v;
        int t = j >> 4, n = j & 15, ks = k >> 5, quad = (k >> 3) & 3, e = k & 7;
        int off = ((t * 4 + ks) * 64 + quad * 16 + n) * 8 + e;
        bh[off] = hv;
        bl[off] = (__bf16)(v - (float)hv);
    }
}

__global__ void k_prep_out(const float* __restrict__ Wout, __bf16* __restrict__ Bhi, __bf16* __restrict__ Blo) {
    for (int i = threadIdx.x; i < DH * 48; i += 256) {
        int k = i / 48, j = i % 48;
        float v = (j < 40) ? Wout[k * 40 + j] : 0.f;
        __bf16 hv = (__bf16)v;
        int t = j >> 4, n = j & 15, ks = k >> 5, quad = (k >> 3) & 3, e = k & 7;
        int off = ((t * 4 + ks) * 64 + quad * 16 + n) * 8 + e;
        Bhi[off] = hv;
        Blo[off] = (__bf16)(v - (float)hv);
    }
}

__device__ inline void split8(const float* p, bf16x8& hi, bf16x8& lo) {
    f32x4 v0 = *(const f32x4*)p;
    f32x4 v1 = *(const f32x4*)(p + 4);
#pragma unroll
    for (int j = 0; j < 4; ++j) {
        __bf16 h0 = (__bf16)v0[j];
        hi[j] = h0;
        lo[j] = (__bf16)(v0[j] - (float)h0);
        __bf16 h1 = (__bf16)v1[j];
        hi[4 + j] = h1;
        lo[4 + j] = (__bf16)(v1[j] - (float)h1);
    }
}

#define MFMA(a, b, c) __builtin_amdgcn_mfma_f32_16x16x32_bf16(a, b, c, 0, 0, 0)

// ---------------- FUSED SpMM + mix + layer GEMM ----------------
// SpMM is laid out so each lane accumulates exactly its MFMA A-fragment:
// lane (n = lane&15, quad = lane>>4) owns node r0+n, feats quad*8 + ks*32 + c
// (ks=0..3, c=0..7) -> 32 fp32 regs == the A fragment for the 4 K-steps.
// The spmm result never touches global memory: convert to bf16 in-reg and MFMA.
__global__ __launch_bounds__(256) void k_spmm_gemm(const __bf16* __restrict__ hin, const __bf16* __restrict__ x0,
                                                   const int* __restrict__ rp, const int2* __restrict__ ep,
                                                   __bf16* __restrict__ aout,
                                                   const __bf16* __restrict__ Bhi, const __bf16* __restrict__ Blo,
                                                   float* __restrict__ stats32) {
    __shared__ __bf16 Bs[2 * DH * DH];  // [hi|lo] in MFMA fragment order
    __shared__ float red[2][4][DH];
    int tid = threadIdx.x;
    {
        const f32x4* sh = (const f32x4*)Bhi;
        const f32x4* sl = (const f32x4*)Blo;
        f32x4* dh = (f32x4*)Bs;
        f32x4* dl = (f32x4*)(Bs + DH * DH);
#pragma unroll
        for (int i = 0; i < 8; ++i) {
            dh[tid + i * 256] = sh[tid + i * 256];
            dl[tid + i * 256] = sl[tid + i * 256];
        }
    }
    // no sync yet: gather phase doesn't touch Bs; sync sits right before MFMA.

    int wave = tid >> 6, lane = tid & 63;
    int n = lane & 15, quad = lane >> 4;
    int r0 = blockIdx.x * 64 + wave * 16;
    int node = r0 + n;
    int nc = (node < NN) ? node : (NN - 1);

    // spmm acc = 0.1*x0 + 0.9*Adj@h, feats quad*8 + ks*32 + c
    float acc[4][8];
    {
        const __bf16* px = x0 + (size_t)nc * DH + quad * 8;
#pragma unroll
        for (int ks = 0; ks < 4; ++ks) {
            bf16x8 xv = *(const bf16x8*)(px + ks * 32);
#pragma unroll
            for (int c = 0; c < 8; ++c) acc[ks][c] = 0.1f * (float)xv[c];
        }
    }
    int s = 0, e = 0;
    if (node < NN) { s = rp[node]; e = rp[node + 1]; }  // rp OOB guard for padded rows
    const __bf16* hq = hin + quad * 8;
    int j = s;
    for (; j + 1 < e; j += 2) {
        int2 p0 = ep[j], p1 = ep[j + 1];
        float w0 = __int_as_float(p0.y), w1 = __int_as_float(p1.y);
        const __bf16* q0 = hq + (size_t)p0.x * DH;
        const __bf16* q1 = hq + (size_t)p1.x * DH;
#pragma unroll
        for (int ks = 0; ks < 4; ++ks) {
            bf16x8 v0 = *(const bf16x8*)(q0 + ks * 32);
            bf16x8 v1 = *(const bf16x8*)(q1 + ks * 32);
#pragma unroll
            for (int c = 0; c < 8; ++c) {
                acc[ks][c] = fmaf(w0, (float)v0[c], acc[ks][c]);
                acc[ks][c] = fmaf(w1, (float)v1[c], acc[ks][c]);
            }
        }
    }
    if (j < e) {
        int2 p = ep[j];
        float w = __int_as_float(p.y);
        const __bf16* qp = hq + (size_t)p.x * DH;
#pragma unroll
        for (int ks = 0; ks < 4; ++ks) {
            bf16x8 v = *(const bf16x8*)(qp + ks * 32);
#pragma unroll
            for (int c = 0; c < 8; ++c) acc[ks][c] = fmaf(w, (float)v[c], acc[ks][c]);
        }
    }

    // in-register A fragments (same bf16 rounding point as the old a-store)
    bf16x8 av[4];
#pragma unroll
    for (int ks = 0; ks < 4; ++ks)
#pragma unroll
        for (int c = 0; c < 8; ++c) av[ks][c] = (__bf16)acc[ks][c];

    __syncthreads();  // Bs staging complete across all waves

    f32x4 gacc[8];
#pragma unroll
    for (int t = 0; t < 8; ++t) gacc[t] = (f32x4){0.f, 0.f, 0.f, 0.f};

#pragma unroll
    for (int ks = 0; ks < 4; ++ks) {
#pragma unroll
        for (int t = 0; t < 8; ++t) {
            int base = ((t * 4 + ks) * 64 + lane) * 8;
            bf16x8 bh = *(const bf16x8*)&Bs[base];
            bf16x8 bl = *(const bf16x8*)&Bs[DH * DH + base];
            gacc[t] = MFMA(av[ks], bh, gacc[t]);
            gacc[t] = MFMA(av[ks], bl, gacc[t]);
        }
    }

#pragma unroll
    for (int t = 0; t < 8; ++t) {
        float sm = 0.f, qq = 0.f;
#pragma unroll
        for (int r = 0; r < 4; ++r) {
            int row = r0 + quad * 4 + r;
            float v = gacc[t][r];
            if (row < NN) {
                aout[(size_t)row * DH + t * 16 + n] = (__bf16)v;
                sm += v;
                qq += v * v;
            }
        }
        sm += __shfl_xor(sm, 16); sm += __shfl_xor(sm, 32);
        qq += __shfl_xor(qq, 16); qq += __shfl_xor(qq, 32);
        if (quad == 0) {
            red[0][wave][t * 16 + n] = sm;
            red[1][wave][t * 16 + n] = qq;
        }
    }
    __syncthreads();
    {
        int which = tid >> 7, jj = tid & 127;
        float tot = red[which][0][jj] + red[which][1][jj] + red[which][2][jj] + red[which][3][jj];
        atomicAdd(&stats32[(size_t)(blockIdx.x & (NSLOT - 1)) * 256 + tid], tot);
    }
}

// ---------------- input GEMM: x0 = relu(X @ Win + bin), fp32 A split on the fly, B in LDS ----------------
__global__ __launch_bounds__(256) void k_lin_in(const float* __restrict__ X,
                                                const __bf16* __restrict__ Bhi, const __bf16* __restrict__ Blo,
                                                const float* __restrict__ bin, __bf16* __restrict__ x0) {
    __shared__ __bf16 Bs[2 * DH * DH];
    int tid = threadIdx.x;
    {
        const f32x4* sh = (const f32x4*)Bhi;
        const f32x4* sl = (const f32x4*)Blo;
        f32x4* dh = (f32x4*)Bs;
        f32x4* dl = (f32x4*)(Bs + DH * DH);
#pragma unroll
        for (int i = 0; i < 8; ++i) {
            dh[tid + i * 256] = sh[tid + i * 256];
            dl[tid + i * 256] = sl[tid + i * 256];
        }
    }
    __syncthreads();

    int wave = tid >> 6, lane = tid & 63;
    int n = lane & 15, quad = lane >> 4;
    int r0 = blockIdx.x * 64 + wave * 16;
    int arow = r0 + n;
    if (arow > NN - 1) arow = NN - 1;
    const float* pa = X + (size_t)arow * DH + quad * 8;

    f32x4 acc[8];
#pragma unroll
    for (int t = 0; t < 8; ++t) acc[t] = (f32x4){0.f, 0.f, 0.f, 0.f};

#pragma unroll
    for (int ks = 0; ks < 4; ++ks) {
        bf16x8 ah, al;
        split8(pa + ks * 32, ah, al);
#pragma unroll
        for (int t = 0; t < 8; ++t) {
            int base = ((t * 4 + ks) * 64 + lane) * 8;
            bf16x8 bh = *(const bf16x8*)&Bs[base];
            bf16x8 bl = *(const bf16x8*)&Bs[DH * DH + base];
            acc[t] = MFMA(ah, bh, acc[t]);
            acc[t] = MFMA(al, bh, acc[t]);
            acc[t] = MFMA(ah, bl, acc[t]);
        }
    }

#pragma unroll
    for (int t = 0; t < 8; ++t) {
        float bj = bin[t * 16 + n];
#pragma unroll
        for (int r = 0; r < 4; ++r) {
            int row = r0 + quad * 4 + r;
            if (row < NN) {
                float v = fmaxf(acc[t][r] + bj, 0.f);
                x0[(size_t)row * DH + t * 16 + n] = (__bf16)v;
            }
        }
    }
}

// ---------------- output GEMM: out = h @ Wout + bout (3 tiles of 16 cols), B in LDS ----------------
__global__ __launch_bounds__(256) void k_gemm_out(const __bf16* __restrict__ A,
                                                  const __bf16* __restrict__ Bhi, const __bf16* __restrict__ Blo,
                                                  const float* __restrict__ bout, float* __restrict__ out) {
    __shared__ __bf16 Bs[2 * 48 * DH];
    int tid = threadIdx.x;
    {
        const f32x4* sh = (const f32x4*)Bhi;
        const f32x4* sl = (const f32x4*)Blo;
        f32x4* dh = (f32x4*)Bs;
        f32x4* dl = (f32x4*)(Bs + 48 * DH);
#pragma unroll
        for (int i = 0; i < 3; ++i) {
            dh[tid + i * 256] = sh[tid + i * 256];
            dl[tid + i * 256] = sl[tid + i * 256];
        }
    }
    __syncthreads();

    int wave = tid >> 6, lane = tid & 63;
    int n = lane & 15, quad = lane >> 4;
    int r0 = blockIdx.x * 64 + wave * 16;
    int arow = r0 + n;
    if (arow > NN - 1) arow = NN - 1;
    const __bf16* pa = A + (size_t)arow * DH + quad * 8;

    f32x4 acc[3];
#pragma unroll
    for (int t = 0; t < 3; ++t) acc[t] = (f32x4){0.f, 0.f, 0.f, 0.f};

#pragma unroll
    for (int ks = 0; ks < 4; ++ks) {
        bf16x8 av = *(const bf16x8*)(pa + ks * 32);
#pragma unroll
        for (int t = 0; t < 3; ++t) {
            int base = ((t * 4 + ks) * 64 + lane) * 8;
            bf16x8 bh = *(const bf16x8*)&Bs[base];
            bf16x8 bl = *(const bf16x8*)&Bs[48 * DH + base];
            acc[t] = MFMA(av, bh, acc[t]);
            acc[t] = MFMA(av, bl, acc[t]);
        }
    }

#pragma unroll
    for (int t = 0; t < 3; ++t) {
        int j = t * 16 + n;
        float bj = (j < 40) ? bout[j] : 0.f;
#pragma unroll
        for (int r = 0; r < 4; ++r) {
            int row = r0 + quad * 4 + r;
            if (row < NN && j < 40) out[(size_t)row * 40 + j] = acc[t][r] + bj;
        }
    }
}

// ---------------- fused slot-reduce + BN-finalize + update: h_out = relu(a*sc + sh + h_in) ----------------
__global__ __launch_bounds__(256) void k_update(const __bf16* __restrict__ a, const __bf16* __restrict__ hin,
                                                __bf16* __restrict__ hout, const float* __restrict__ stats32,
                                                const float* __restrict__ gamma, const float* __restrict__ bbeta) {
    __shared__ float scb[DH], shb[DH];
    int tid = threadIdx.x;
    if (tid < DH) {
        float s = 0.f, q = 0.f;
#pragma unroll
        for (int sl = 0; sl < NSLOT; ++sl) {
            s += stats32[(size_t)sl * 256 + tid];
            q += stats32[(size_t)sl * 256 + 128 + tid];
        }
        float mu = s * (1.0f / NN);
        float var = q * (1.0f / NN) - mu * mu;
        if (var < 0.f) var = 0.f;
        float sc = gamma[tid] * rsqrtf(var + 1e-5f);
        scb[tid] = sc;
        shb[tid] = bbeta[tid] - mu * sc;
    }
    __syncthreads();

    int idx = blockIdx.x * 256 + tid;
    int j0 = (idx & 15) * 8;
    bf16x8 av = ((const bf16x8*)a)[idx];
    bf16x8 hv = ((const bf16x8*)hin)[idx];
    bf16x8 o;
#pragma unroll
    for (int c = 0; c < 8; ++c) {
        int j = j0 + c;
        float v = fmaxf(fmaf((float)av[c], scb[j], shb[j]) + (float)hv[c], 0.f);
        o[c] = (__bf16)v;
    }
    ((bf16x8*)hout)[idx] = o;
}

extern "C" void kernel_launch(void* const* d_in, const int* in_sizes, int n_in,
                              void* d_out, int out_size, void* d_ws, size_t ws_size,
                              hipStream_t stream) {
    const float* x = (const float*)d_in[0];
    const float* ew = (const float*)d_in[1];
    const float* Win = (const float*)d_in[2];
    const float* bin = (const float*)d_in[3];
    const float* convW = (const float*)d_in[4];
    const float* gamma = (const float*)d_in[5];
    const float* bbeta = (const float*)d_in[6];
    const float* Wout = (const float*)d_in[7];
    const float* bout = (const float*)d_in[8];
    const int* erow = (const int*)d_in[9];
    const int* ecol = (const int*)d_in[10];
    float* out = (float*)d_out;

    char* wsp = (char*)d_ws;
    size_t off = 0;
    auto alloc = [&](size_t bytes) -> void* {
        void* p = wsp + off;
        off += (bytes + 255) & ~(size_t)255;
        return p;
    };
    __bf16* x0 = (__bf16*)alloc((size_t)NN * DH * 2);
    __bf16* h = (__bf16*)alloc((size_t)NN * DH * 2);
    __bf16* a = (__bf16*)alloc((size_t)NN * DH * 2);
    int* rp = (int*)alloc((NN + 1) * 4);
    // zero-init region: cnt | fil | stats32 as ONE memset
    size_t zero_bytes = (size_t)NN * 4 + (size_t)NN * 4 + (size_t)NL * NSLOT * 256 * 4;
    int* cnt = (int*)alloc(zero_bytes);
    int* fil = cnt + NN;
    float* stats32 = (float*)(fil + NN);
    int2* ep = (int2*)alloc((size_t)EE * 8);
    int* part = (int*)alloc(256 * 4);
    __bf16* Bhi = (__bf16*)alloc((size_t)(NL + 1) * DH * DH * 2);
    __bf16* Blo = (__bf16*)alloc((size_t)(NL + 1) * DH * DH * 2);
    __bf16* Bohi = (__bf16*)alloc((size_t)DH * 48 * 2);
    __bf16* Bolo = (__bf16*)alloc((size_t)DH * 48 * 2);

    hipMemsetAsync(cnt, 0, zero_bytes, stream);

    k_hist<<<3125, 256, 0, stream>>>(erow, cnt);
    k_scan1<<<196, 512, 0, stream>>>(cnt, rp, part);
    k_scan2<<<1, 256, 0, stream>>>(part, 196);
    k_scan3<<<196, 512, 0, stream>>>(rp, part);
    k_fill<<<3125, 256, 0, stream>>>(erow, ecol, ew, rp, fil, ep);

    k_prep_w<<<NL + 1, 256, 0, stream>>>(convW, Win, Bhi, Blo);
    k_prep_out<<<1, 256, 0, stream>>>(Wout, Bohi, Bolo);

    k_lin_in<<<GEMM_GRID, 256, 0, stream>>>(x, Bhi + (size_t)NL * DH * DH, Blo + (size_t)NL * DH * DH, bin, x0);

    for (int l = 0; l < NL; ++l) {
        const __bf16* hin = (l == 0) ? x0 : h;
        float* st = stats32 + (size_t)l * NSLOT * 256;
        k_spmm_gemm<<<GEMM_GRID, 256, 0, stream>>>(hin, x0, rp, ep, a,
                                                   Bhi + (size_t)l * DH * DH, Blo + (size_t)l * DH * DH, st);
        k_update<<<6250, 256, 0, stream>>>(a, hin, h, st, gamma + l * DH, bbeta + l * DH);
    }
    k_gemm_out<<<GEMM_GRID, 256, 0, stream>>>(h, Bohi, Bolo, bout, out);
}

// Round 2
// 1417.828 us; speedup vs baseline: 1.0592x; 1.0592x over previous
//
#include <hip/hip_runtime.h>
#include <math.h>

#define NN 100000
#define EE 800000
#define DH 128
#define NL 16
#define GEMM_GRID 1563
#define SG_GRID 782      // ceil(100000 / 128) for 8-wave spmm_gemm blocks
#define NSLOT 32

typedef __bf16 bf16x8 __attribute__((ext_vector_type(8)));
typedef __bf16 bf16x2 __attribute__((ext_vector_type(2)));
typedef float f32x4 __attribute__((ext_vector_type(4)));

// ---------------- CSR build ----------------
__global__ void k_hist(const int* __restrict__ row, int* __restrict__ cnt) {
    int e = blockIdx.x * 256 + threadIdx.x;
    if (e < EE) atomicAdd(&cnt[row[e]], 1);
}

__global__ void k_scan1(const int* __restrict__ cnt, int* __restrict__ rp, int* __restrict__ part) {
    __shared__ int buf[512];
    int tid = threadIdx.x;
    int i = blockIdx.x * 512 + tid;
    int v = (i < NN) ? cnt[i] : 0;
    buf[tid] = v;
    __syncthreads();
    for (int off = 1; off < 512; off <<= 1) {
        int x = (tid >= off) ? buf[tid - off] : 0;
        __syncthreads();
        buf[tid] += x;
        __syncthreads();
    }
    if (i < NN) rp[i] = buf[tid] - v;
    if (tid == 511) part[blockIdx.x] = buf[511];
}

__global__ void k_scan2(int* __restrict__ part, int nparts) {
    __shared__ int buf[256];
    int tid = threadIdx.x;
    int v = (tid < nparts) ? part[tid] : 0;
    buf[tid] = v;
    __syncthreads();
    for (int off = 1; off < 256; off <<= 1) {
        int x = (tid >= off) ? buf[tid - off] : 0;
        __syncthreads();
        buf[tid] += x;
        __syncthreads();
    }
    if (tid < nparts) part[tid] = buf[tid] - v;
}

__global__ void k_scan3(int* __restrict__ rp, const int* __restrict__ part) {
    int i = blockIdx.x * 512 + threadIdx.x;
    if (i < NN) rp[i] += part[blockIdx.x];
    if (i == 0) rp[NN] = EE;
}

// w prescaled by (1-ALPHA)=0.9 so the gather loop is a pure fma chain
__global__ void k_fill(const int* __restrict__ row, const int* __restrict__ col,
                       const float* __restrict__ w, const int* __restrict__ rp,
                       int* __restrict__ fil, int2* __restrict__ ep) {
    int e = blockIdx.x * 256 + threadIdx.x;
    if (e >= EE) return;
    int r = row[e];
    int pos = rp[r] + atomicAdd(&fil[r], 1);
    ep[pos] = make_int2(col[e], __float_as_int(0.9f * w[e]));
}

// ---------------- weight prep: split hi/lo bf16 + swizzle to MFMA fragment order ----------------
// frag[t][ks][lane][e] = M[k][j], j = t*16 + (lane&15), k = ks*32 + (lane>>4)*8 + e
__global__ void k_prep_w(const float* __restrict__ convW, const float* __restrict__ Win,
                         __bf16* __restrict__ Bhi, __bf16* __restrict__ Blo) {
    int l = blockIdx.x;
    const float* W;
    float beta, ob;
    if (l < NL) {
        beta = logf(0.5f / (float)(l + 1) + 1.0f);
        ob = 1.0f - beta;
        W = convW + (size_t)l * DH * DH;
    } else {
        beta = 1.0f;
        ob = 0.0f;
        W = Win;
    }
    __bf16* bh = Bhi + (size_t)l * DH * DH;
    __bf16* bl = Blo + (size_t)l * DH * DH;
    for (int i = threadIdx.x; i < DH * DH; i += 256) {
        int k = i >> 7, j = i & 127;
        float v = beta * W[i] + ((k == j) ? ob : 0.f);
        __bf16 hv = (__bf16)v;
        int t = j >> 4, n = j & 15, ks = k >> 5, quad = (k >> 3) & 3, e = k & 7;
        int off = ((t * 4 + ks) * 64 + quad * 16 + n) * 8 + e;
        bh[off] = hv;
        bl[off] = (__bf16)(v - (float)hv);
    }
}

__global__ void k_prep_out(const float* __restrict__ Wout, __bf16* __restrict__ Bhi, __bf16* __restrict__ Blo) {
    for (int i = threadIdx.x; i < DH * 48; i += 256) {
        int k = i / 48, j = i % 48;
        float v = (j < 40) ? Wout[k * 40 + j] : 0.f;
        __bf16 hv = (__bf16)v;
        int t = j >> 4, n = j & 15, ks = k >> 5, quad = (k >> 3) & 3, e = k & 7;
        int off = ((t * 4 + ks) * 64 + quad * 16 + n) * 8 + e;
        Bhi[off] = hv;
        Blo[off] = (__bf16)(v - (float)hv);
    }
}

__device__ inline void split8(const float* p, bf16x8& hi, bf16x8& lo) {
    f32x4 v0 = *(const f32x4*)p;
    f32x4 v1 = *(const f32x4*)(p + 4);
#pragma unroll
    for (int j = 0; j < 4; ++j) {
        __bf16 h0 = (__bf16)v0[j];
        hi[j] = h0;
        lo[j] = (__bf16)(v0[j] - (float)h0);
        __bf16 h1 = (__bf16)v1[j];
        hi[4 + j] = h1;
        lo[4 + j] = (__bf16)(v1[j] - (float)h1);
    }
}

#define MFMA(a, b, c) __builtin_amdgcn_mfma_f32_16x16x32_bf16(a, b, c, 0, 0, 0)

// ---------------- FUSED SpMM + mix + layer GEMM ----------------
// 8 waves (512 threads) per block: same 64 KB B-tile now amortized over 2x the
// waves -> 16 waves/CU (vs 8 before) at an unchanged 2 blocks/CU LDS budget.
// The gather is latency-bound (ep[j] -> addr -> row load chain), so occupancy
// is the lever. VGPR=88 fits the 4 waves/SIMD cap (<=128), pinned by
// __launch_bounds__(512, 4).
__global__ __launch_bounds__(512, 4) void k_spmm_gemm(const __bf16* __restrict__ hin, const __bf16* __restrict__ x0,
                                                      const int* __restrict__ rp, const int2* __restrict__ ep,
                                                      __bf16* __restrict__ aout,
                                                      const __bf16* __restrict__ Bhi, const __bf16* __restrict__ Blo,
                                                      float* __restrict__ stats32) {
    __shared__ __bf16 Bs[2 * DH * DH];  // [hi|lo] in MFMA fragment order
    __shared__ float red[2][8][DH];
    int tid = threadIdx.x;
    {
        const f32x4* sh = (const f32x4*)Bhi;
        const f32x4* sl = (const f32x4*)Blo;
        f32x4* dh = (f32x4*)Bs;
        f32x4* dl = (f32x4*)(Bs + DH * DH);
#pragma unroll
        for (int i = 0; i < 4; ++i) {
            dh[tid + i * 512] = sh[tid + i * 512];
            dl[tid + i * 512] = sl[tid + i * 512];
        }
    }
    // no sync yet: gather phase doesn't touch Bs; sync sits right before MFMA.

    int wave = tid >> 6, lane = tid & 63;
    int n = lane & 15, quad = lane >> 4;
    int r0 = blockIdx.x * 128 + wave * 16;
    int node = r0 + n;
    int nc = (node < NN) ? node : (NN - 1);

    // spmm acc = 0.1*x0 + 0.9*Adj@h, feats quad*8 + ks*32 + c
    float acc[4][8];
    {
        const __bf16* px = x0 + (size_t)nc * DH + quad * 8;
#pragma unroll
        for (int ks = 0; ks < 4; ++ks) {
            bf16x8 xv = *(const bf16x8*)(px + ks * 32);
#pragma unroll
            for (int c = 0; c < 8; ++c) acc[ks][c] = 0.1f * (float)xv[c];
        }
    }
    int s = 0, e = 0;
    if (node < NN) { s = rp[node]; e = rp[node + 1]; }  // rp OOB guard for padded rows
    const __bf16* hq = hin + quad * 8;
    int j = s;
    for (; j + 1 < e; j += 2) {
        int2 p0 = ep[j], p1 = ep[j + 1];
        float w0 = __int_as_float(p0.y), w1 = __int_as_float(p1.y);
        const __bf16* q0 = hq + (size_t)p0.x * DH;
        const __bf16* q1 = hq + (size_t)p1.x * DH;
#pragma unroll
        for (int ks = 0; ks < 4; ++ks) {
            bf16x8 v0 = *(const bf16x8*)(q0 + ks * 32);
            bf16x8 v1 = *(const bf16x8*)(q1 + ks * 32);
#pragma unroll
            for (int c = 0; c < 8; ++c) {
                acc[ks][c] = fmaf(w0, (float)v0[c], acc[ks][c]);
                acc[ks][c] = fmaf(w1, (float)v1[c], acc[ks][c]);
            }
        }
    }
    if (j < e) {
        int2 p = ep[j];
        float w = __int_as_float(p.y);
        const __bf16* qp = hq + (size_t)p.x * DH;
#pragma unroll
        for (int ks = 0; ks < 4; ++ks) {
            bf16x8 v = *(const bf16x8*)(qp + ks * 32);
#pragma unroll
            for (int c = 0; c < 8; ++c) acc[ks][c] = fmaf(w, (float)v[c], acc[ks][c]);
        }
    }

    // in-register A fragments (same bf16 rounding point as the old a-store)
    bf16x8 av[4];
#pragma unroll
    for (int ks = 0; ks < 4; ++ks)
#pragma unroll
        for (int c = 0; c < 8; ++c) av[ks][c] = (__bf16)acc[ks][c];

    __syncthreads();  // Bs staging complete across all waves

    f32x4 gacc[8];
#pragma unroll
    for (int t = 0; t < 8; ++t) gacc[t] = (f32x4){0.f, 0.f, 0.f, 0.f};

#pragma unroll
    for (int ks = 0; ks < 4; ++ks) {
#pragma unroll
        for (int t = 0; t < 8; ++t) {
            int base = ((t * 4 + ks) * 64 + lane) * 8;
            bf16x8 bh = *(const bf16x8*)&Bs[base];
            bf16x8 bl = *(const bf16x8*)&Bs[DH * DH + base];
            gacc[t] = MFMA(av[ks], bh, gacc[t]);
            gacc[t] = MFMA(av[ks], bl, gacc[t]);
        }
    }

#pragma unroll
    for (int t = 0; t < 8; ++t) {
        float sm = 0.f, qq = 0.f;
#pragma unroll
        for (int r = 0; r < 4; ++r) {
            int row = r0 + quad * 4 + r;
            float v = gacc[t][r];
            if (row < NN) {
                aout[(size_t)row * DH + t * 16 + n] = (__bf16)v;
                sm += v;
                qq += v * v;
            }
        }
        sm += __shfl_xor(sm, 16); sm += __shfl_xor(sm, 32);
        qq += __shfl_xor(qq, 16); qq += __shfl_xor(qq, 32);
        if (quad == 0) {
            red[0][wave][t * 16 + n] = sm;
            red[1][wave][t * 16 + n] = qq;
        }
    }
    __syncthreads();
    if (tid < 256) {
        int which = tid >> 7, jj = tid & 127;
        float tot = 0.f;
#pragma unroll
        for (int w = 0; w < 8; ++w) tot += red[which][w][jj];
        atomicAdd(&stats32[(size_t)(blockIdx.x & (NSLOT - 1)) * 256 + tid], tot);
    }
}

// ---------------- input GEMM: x0 = relu(X @ Win + bin), fp32 A split on the fly, B in LDS ----------------
__global__ __launch_bounds__(256) void k_lin_in(const float* __restrict__ X,
                                                const __bf16* __restrict__ Bhi, const __bf16* __restrict__ Blo,
                                                const float* __restrict__ bin, __bf16* __restrict__ x0) {
    __shared__ __bf16 Bs[2 * DH * DH];
    int tid = threadIdx.x;
    {
        const f32x4* sh = (const f32x4*)Bhi;
        const f32x4* sl = (const f32x4*)Blo;
        f32x4* dh = (f32x4*)Bs;
        f32x4* dl = (f32x4*)(Bs + DH * DH);
#pragma unroll
        for (int i = 0; i < 8; ++i) {
            dh[tid + i * 256] = sh[tid + i * 256];
            dl[tid + i * 256] = sl[tid + i * 256];
        }
    }
    __syncthreads();

    int wave = tid >> 6, lane = tid & 63;
    int n = lane & 15, quad = lane >> 4;
    int r0 = blockIdx.x * 64 + wave * 16;
    int arow = r0 + n;
    if (arow > NN - 1) arow = NN - 1;
    const float* pa = X + (size_t)arow * DH + quad * 8;

    f32x4 acc[8];
#pragma unroll
    for (int t = 0; t < 8; ++t) acc[t] = (f32x4){0.f, 0.f, 0.f, 0.f};

#pragma unroll
    for (int ks = 0; ks < 4; ++ks) {
        bf16x8 ah, al;
        split8(pa + ks * 32, ah, al);
#pragma unroll
        for (int t = 0; t < 8; ++t) {
            int base = ((t * 4 + ks) * 64 + lane) * 8;
            bf16x8 bh = *(const bf16x8*)&Bs[base];
            bf16x8 bl = *(const bf16x8*)&Bs[DH * DH + base];
            acc[t] = MFMA(ah, bh, acc[t]);
            acc[t] = MFMA(al, bh, acc[t]);
            acc[t] = MFMA(ah, bl, acc[t]);
        }
    }

#pragma unroll
    for (int t = 0; t < 8; ++t) {
        float bj = bin[t * 16 + n];
#pragma unroll
        for (int r = 0; r < 4; ++r) {
            int row = r0 + quad * 4 + r;
            if (row < NN) {
                float v = fmaxf(acc[t][r] + bj, 0.f);
                x0[(size_t)row * DH + t * 16 + n] = (__bf16)v;
            }
        }
    }
}

// ---------------- output GEMM: out = h @ Wout + bout (3 tiles of 16 cols), B in LDS ----------------
__global__ __launch_bounds__(256) void k_gemm_out(const __bf16* __restrict__ A,
                                                  const __bf16* __restrict__ Bhi, const __bf16* __restrict__ Blo,
                                                  const float* __restrict__ bout, float* __restrict__ out) {
    __shared__ __bf16 Bs[2 * 48 * DH];
    int tid = threadIdx.x;
    {
        const f32x4* sh = (const f32x4*)Bhi;
        const f32x4* sl = (const f32x4*)Blo;
        f32x4* dh = (f32x4*)Bs;
        f32x4* dl = (f32x4*)(Bs + 48 * DH);
#pragma unroll
        for (int i = 0; i < 3; ++i) {
            dh[tid + i * 256] = sh[tid + i * 256];
            dl[tid + i * 256] = sl[tid + i * 256];
        }
    }
    __syncthreads();

    int wave = tid >> 6, lane = tid & 63;
    int n = lane & 15, quad = lane >> 4;
    int r0 = blockIdx.x * 64 + wave * 16;
    int arow = r0 + n;
    if (arow > NN - 1) arow = NN - 1;
    const __bf16* pa = A + (size_t)arow * DH + quad * 8;

    f32x4 acc[3];
#pragma unroll
    for (int t = 0; t < 3; ++t) acc[t] = (f32x4){0.f, 0.f, 0.f, 0.f};

#pragma unroll
    for (int ks = 0; ks < 4; ++ks) {
        bf16x8 av = *(const bf16x8*)(pa + ks * 32);
#pragma unroll
        for (int t = 0; t < 3; ++t) {
            int base = ((t * 4 + ks) * 64 + lane) * 8;
            bf16x8 bh = *(const bf16x8*)&Bs[base];
            bf16x8 bl = *(const bf16x8*)&Bs[48 * DH + base];
            acc[t] = MFMA(av, bh, acc[t]);
            acc[t] = MFMA(av, bl, acc[t]);
        }
    }

#pragma unroll
    for (int t = 0; t < 3; ++t) {
        int j = t * 16 + n;
        float bj = (j < 40) ? bout[j] : 0.f;
#pragma unroll
        for (int r = 0; r < 4; ++r) {
            int row = r0 + quad * 4 + r;
            if (row < NN && j < 40) out[(size_t)row * 40 + j] = acc[t][r] + bj;
        }
    }
}

// ---------------- fused slot-reduce + BN-finalize + update: h_out = relu(a*sc + sh + h_in) ----------------
__global__ __launch_bounds__(256) void k_update(const __bf16* __restrict__ a, const __bf16* __restrict__ hin,
                                                __bf16* __restrict__ hout, const float* __restrict__ stats32,
                                                const float* __restrict__ gamma, const float* __restrict__ bbeta) {
    __shared__ float scb[DH], shb[DH];
    int tid = threadIdx.x;
    if (tid < DH) {
        float s = 0.f, q = 0.f;
#pragma unroll
        for (int sl = 0; sl < NSLOT; ++sl) {
            s += stats32[(size_t)sl * 256 + tid];
            q += stats32[(size_t)sl * 256 + 128 + tid];
        }
        float mu = s * (1.0f / NN);
        float var = q * (1.0f / NN) - mu * mu;
        if (var < 0.f) var = 0.f;
        float sc = gamma[tid] * rsqrtf(var + 1e-5f);
        scb[tid] = sc;
        shb[tid] = bbeta[tid] - mu * sc;
    }
    __syncthreads();

    int idx = blockIdx.x * 256 + tid;
    int j0 = (idx & 15) * 8;
    bf16x8 av = ((const bf16x8*)a)[idx];
    bf16x8 hv = ((const bf16x8*)hin)[idx];
    bf16x8 o;
#pragma unroll
    for (int c = 0; c < 8; ++c) {
        int j = j0 + c;
        float v = fmaxf(fmaf((float)av[c], scb[j], shb[j]) + (float)hv[c], 0.f);
        o[c] = (__bf16)v;
    }
    ((bf16x8*)hout)[idx] = o;
}

extern "C" void kernel_launch(void* const* d_in, const int* in_sizes, int n_in,
                              void* d_out, int out_size, void* d_ws, size_t ws_size,
                              hipStream_t stream) {
    const float* x = (const float*)d_in[0];
    const float* ew = (const float*)d_in[1];
    const float* Win = (const float*)d_in[2];
    const float* bin = (const float*)d_in[3];
    const float* convW = (const float*)d_in[4];
    const float* gamma = (const float*)d_in[5];
    const float* bbeta = (const float*)d_in[6];
    const float* Wout = (const float*)d_in[7];
    const float* bout = (const float*)d_in[8];
    const int* erow = (const int*)d_in[9];
    const int* ecol = (const int*)d_in[10];
    float* out = (float*)d_out;

    char* wsp = (char*)d_ws;
    size_t off = 0;
    auto alloc = [&](size_t bytes) -> void* {
        void* p = wsp + off;
        off += (bytes + 255) & ~(size_t)255;
        return p;
    };
    __bf16* x0 = (__bf16*)alloc((size_t)NN * DH * 2);
    __bf16* h = (__bf16*)alloc((size_t)NN * DH * 2);
    __bf16* a = (__bf16*)alloc((size_t)NN * DH * 2);
    int* rp = (int*)alloc((NN + 1) * 4);
    // zero-init region: cnt | fil | stats32 as ONE memset
    size_t zero_bytes = (size_t)NN * 4 + (size_t)NN * 4 + (size_t)NL * NSLOT * 256 * 4;
    int* cnt = (int*)alloc(zero_bytes);
    int* fil = cnt + NN;
    float* stats32 = (float*)(fil + NN);
    int2* ep = (int2*)alloc((size_t)EE * 8);
    int* part = (int*)alloc(256 * 4);
    __bf16* Bhi = (__bf16*)alloc((size_t)(NL + 1) * DH * DH * 2);
    __bf16* Blo = (__bf16*)alloc((size_t)(NL + 1) * DH * DH * 2);
    __bf16* Bohi = (__bf16*)alloc((size_t)DH * 48 * 2);
    __bf16* Bolo = (__bf16*)alloc((size_t)DH * 48 * 2);

    hipMemsetAsync(cnt, 0, zero_bytes, stream);

    k_hist<<<3125, 256, 0, stream>>>(erow, cnt);
    k_scan1<<<196, 512, 0, stream>>>(cnt, rp, part);
    k_scan2<<<1, 256, 0, stream>>>(part, 196);
    k_scan3<<<196, 512, 0, stream>>>(rp, part);
    k_fill<<<3125, 256, 0, stream>>>(erow, ecol, ew, rp, fil, ep);

    k_prep_w<<<NL + 1, 256, 0, stream>>>(convW, Win, Bhi, Blo);
    k_prep_out<<<1, 256, 0, stream>>>(Wout, Bohi, Bolo);

    k_lin_in<<<GEMM_GRID, 256, 0, stream>>>(x, Bhi + (size_t)NL * DH * DH, Blo + (size_t)NL * DH * DH, bin, x0);

    for (int l = 0; l < NL; ++l) {
        const __bf16* hin = (l == 0) ? x0 : h;
        float* st = stats32 + (size_t)l * NSLOT * 256;
        k_spmm_gemm<<<SG_GRID, 512, 0, stream>>>(hin, x0, rp, ep, a,
                                                 Bhi + (size_t)l * DH * DH, Blo + (size_t)l * DH * DH, st);
        k_update<<<6250, 256, 0, stream>>>(a, hin, h, st, gamma + l * DH, bbeta + l * DH);
    }
    k_gemm_out<<<GEMM_GRID, 256, 0, stream>>>(h, Bohi, Bolo, bout, out);
}